// Round 9
// baseline (164.522 us; speedup 1.0000x reference)
//
#include <hip/hip_runtime.h>
#include <hip/hip_bf16.h>

// DeformableTemporalAttention — MI355X (gfx950)
// B=4, N=4096 (64x64), T=3, D=256, H=8, P=9, dh=32
//
// Pipeline (4 dispatches):
//  1. prep    : asum = sum_t x -> fp16 hi/lo;  xmid -> fp16 hi/lo;
//               weights transposed to fp16 [n][k] (W_off/W_attn also lo); bcat
//  2. mgemm01 : fused  valsum(fp16) = asum @ W_v + 3*b_v   (2-pass fp16)
//                      proj(f32)    = xmid @ [W_off|W_attn] + bcat (3-pass)
//               BM=BN=BK=64, reg-prefetch pipeline, XCD-swizzled grid
//  3. sample4 : 4 pixels / 256-thr block, attn folded into corner weights,
//               fp16 gathers -> inter fp16 hi/lo
//  4. mgemm2  : out = inter @ W_o + b_o   (2-pass fp16, XCD-swizzled)

#define NH_ 8
#define DH_ 32
#define MM_ 16384   // B*N

typedef __attribute__((ext_vector_type(8))) _Float16 f16x8;
typedef __attribute__((ext_vector_type(4))) _Float16 f16x4;
typedef __attribute__((ext_vector_type(4))) float f32x4;

struct HL { _Float16 h, l; };
static __device__ __forceinline__ HL fsplit(float f) {
  HL r;
  r.h = (_Float16)f;
  r.l = (_Float16)(f - (float)r.h);
  return r;
}

// ---------------- prep: A-side splits + weight transpose/splits ------------
__global__ __launch_bounds__(256) void prep(
    const float* __restrict__ x,
    const float* __restrict__ W_off, const float* __restrict__ W_attn,
    const float* __restrict__ W_v, const float* __restrict__ W_o,
    const float* __restrict__ b_off, const float* __restrict__ b_attn,
    _Float16* __restrict__ ash, _Float16* __restrict__ asl,
    _Float16* __restrict__ xmh, _Float16* __restrict__ xml,
    _Float16* __restrict__ wv, _Float16* __restrict__ wch,
    _Float16* __restrict__ wcl, _Float16* __restrict__ wo,
    float* __restrict__ bcat) {
  const int bid = blockIdx.x, t = threadIdx.x;
  if (bid < 4096) {
    const int gid = bid * 256 + t;
    const int row = gid >> 6, c4 = (gid & 63) * 4;
    const float* xr = x + (size_t)row * 768 + c4;
    float4 a0 = *(const float4*)xr;
    float4 a1 = *(const float4*)(xr + 256);
    float4 a2 = *(const float4*)(xr + 512);
    float s[4] = {a0.x + a1.x + a2.x, a0.y + a1.y + a2.y,
                  a0.z + a1.z + a2.z, a0.w + a1.w + a2.w};
    float m[4] = {a1.x, a1.y, a1.z, a1.w};
    f16x4 shv, slv, mhv, mlv;
#pragma unroll
    for (int j = 0; j < 4; ++j) {
      HL sj = fsplit(s[j]);
      shv[j] = sj.h; slv[j] = sj.l;
      HL mj = fsplit(m[j]);
      mhv[j] = mj.h; mlv[j] = mj.l;
    }
    const size_t o = (size_t)row * 256 + c4;
    *(f16x4*)(ash + o) = shv;  *(f16x4*)(asl + o) = slv;
    *(f16x4*)(xmh + o) = mhv;  *(f16x4*)(xml + o) = mlv;
  } else {
    const int n = bid - 4096;
    wv[n * 256 + t] = (_Float16)W_v[(size_t)t * 256 + n];
    wo[n * 256 + t] = (_Float16)W_o[(size_t)t * 256 + n];
    if (n < 216) {
      float v = (n < 144) ? W_off[(size_t)t * 144 + n] : W_attn[(size_t)t * 72 + (n - 144)];
      HL w = fsplit(v);
      wch[n * 256 + t] = w.h; wcl[n * 256 + t] = w.l;
    }
    if (n == 0 && t < 216) bcat[t] = (t < 144) ? b_off[t] : b_attn[t - 144];
  }
}

// ---------------- fused GEMM: valsum (2-pass) + proj (3-pass) --------------
// BM=64, BN=64, BK=64; 4 waves (2x2), each wave 32x32. Reg-prefetch pipeline.
// Grid: 2048 1-D, XCD-swizzled; flat = m*8 + y; y<4 -> valsum, y>=4 -> proj.
__global__ __launch_bounds__(256, 4) void mgemm01(
    const _Float16* __restrict__ Ahi, const _Float16* __restrict__ Alo,
    const _Float16* __restrict__ Xmh, const _Float16* __restrict__ Xml,
    const _Float16* __restrict__ Wv, const _Float16* __restrict__ Wch,
    const _Float16* __restrict__ Wcl,
    const float* __restrict__ b_v, const float* __restrict__ bcat,
    _Float16* __restrict__ valsum, float* __restrict__ proj) {
  __shared__ _Float16 Ah[64][64], Al[64][64], Bh[64][64], Bl[64][64];
  const int bid = blockIdx.x;
  const int flat = (bid & 7) * 256 + (bid >> 3);   // XCD-chunked (2048 % 8 == 0)
  const int m0 = (flat >> 3) * 64;
  const int yy = flat & 7;
  const int mode1 = yy >= 4;
  const int n0 = (yy & 3) * 64;
  const int tid = threadIdx.x, wid = tid >> 6, lane = tid & 63;
  const int am = (wid >> 1) * 32, bn = (wid & 1) * 32;
  const int fr = lane & 15, kg = lane >> 4;
  const _Float16* Ahs = mode1 ? Xmh : Ahi;
  const _Float16* Als = mode1 ? Xml : Alo;
  const _Float16* Bhs = mode1 ? Wch : Wv;

  const int r0s = tid >> 3, c0s = tid & 7;   // staging: rows 0..31
  const int r1s = r0s + 32;                  //          rows 32..63
  const int d0s = r0s * 64 + ((c0s ^ (r0s & 7)) * 8);
  const int d1s = r1s * 64 + ((c0s ^ (r1s & 7)) * 8);

  f32x4 acc[2][2];
#pragma unroll
  for (int i = 0; i < 2; ++i)
#pragma unroll
    for (int j = 0; j < 2; ++j) acc[i][j] = (f32x4)(0.f);

  f16x8 pah[2], pal[2], pbh[2], pbl[2];

#define LOADT01(k0)                                                          \
  {                                                                          \
    size_t a0 = (size_t)(m0 + r0s) * 256 + (k0) + c0s * 8;                   \
    size_t a1 = (size_t)(m0 + r1s) * 256 + (k0) + c0s * 8;                   \
    pah[0] = *(const f16x8*)(Ahs + a0); pal[0] = *(const f16x8*)(Als + a0);  \
    pah[1] = *(const f16x8*)(Ahs + a1); pal[1] = *(const f16x8*)(Als + a1);  \
    int nr0 = n0 + r0s, nr1 = n0 + r1s;                                      \
    size_t b0 = (size_t)nr0 * 256 + (k0) + c0s * 8;                          \
    size_t b1 = (size_t)nr1 * 256 + (k0) + c0s * 8;                          \
    if (!mode1 || nr0 < 216) pbh[0] = *(const f16x8*)(Bhs + b0);             \
    else pbh[0] = (f16x8)(_Float16)0.f;                                      \
    if (!mode1 || nr1 < 216) pbh[1] = *(const f16x8*)(Bhs + b1);             \
    else pbh[1] = (f16x8)(_Float16)0.f;                                      \
    if (mode1) {                                                             \
      pbl[0] = (nr0 < 216) ? *(const f16x8*)(Wcl + b0) : (f16x8)(_Float16)0.f;\
      pbl[1] = (nr1 < 216) ? *(const f16x8*)(Wcl + b1) : (f16x8)(_Float16)0.f;\
    }                                                                        \
  }

#define WRITET()                                                             \
  {                                                                          \
    *(f16x8*)(&Ah[0][0] + d0s) = pah[0]; *(f16x8*)(&Al[0][0] + d0s) = pal[0];\
    *(f16x8*)(&Ah[0][0] + d1s) = pah[1]; *(f16x8*)(&Al[0][0] + d1s) = pal[1];\
    *(f16x8*)(&Bh[0][0] + d0s) = pbh[0]; *(f16x8*)(&Bh[0][0] + d1s) = pbh[1];\
    if (mode1) {                                                             \
      *(f16x8*)(&Bl[0][0] + d0s) = pbl[0]; *(f16x8*)(&Bl[0][0] + d1s) = pbl[1];\
    }                                                                        \
  }

#define COMPUTET()                                                           \
  _Pragma("unroll")                                                          \
  for (int ks = 0; ks < 2; ++ks) {                                           \
    const int kc = ks * 4 + kg;                                              \
    f16x8 ah[2], al[2], bh[2];                                               \
    _Pragma("unroll")                                                        \
    for (int mi = 0; mi < 2; ++mi) {                                         \
      int m = am + mi * 16 + fr;                                             \
      int o = m * 64 + ((kc ^ (m & 7)) * 8);                                 \
      ah[mi] = *(const f16x8*)(&Ah[0][0] + o);                               \
      al[mi] = *(const f16x8*)(&Al[0][0] + o);                               \
    }                                                                        \
    _Pragma("unroll")                                                        \
    for (int ni = 0; ni < 2; ++ni) {                                         \
      int nn = bn + ni * 16 + fr;                                            \
      int o = nn * 64 + ((kc ^ (nn & 7)) * 8);                               \
      bh[ni] = *(const f16x8*)(&Bh[0][0] + o);                               \
      _Pragma("unroll")                                                      \
      for (int mi = 0; mi < 2; ++mi) {                                       \
        acc[mi][ni] = __builtin_amdgcn_mfma_f32_16x16x32_f16(ah[mi], bh[ni], acc[mi][ni], 0, 0, 0);\
        acc[mi][ni] = __builtin_amdgcn_mfma_f32_16x16x32_f16(al[mi], bh[ni], acc[mi][ni], 0, 0, 0);\
      }                                                                      \
      if (mode1) {                                                           \
        f16x8 bl = *(const f16x8*)(&Bl[0][0] + o);                           \
        _Pragma("unroll")                                                    \
        for (int mi = 0; mi < 2; ++mi)                                       \
          acc[mi][ni] = __builtin_amdgcn_mfma_f32_16x16x32_f16(ah[mi], bl, acc[mi][ni], 0, 0, 0);\
      }                                                                      \
    }                                                                        \
  }

  LOADT01(0);
  WRITET();
  __syncthreads();
#pragma unroll
  for (int t = 0; t < 4; ++t) {
    if (t < 3) LOADT01((t + 1) * 64);
    COMPUTET();
    __syncthreads();
    if (t < 3) { WRITET(); __syncthreads(); }
  }

  const int ro = kg * 4;
#pragma unroll
  for (int mi = 0; mi < 2; ++mi)
#pragma unroll
    for (int ni = 0; ni < 2; ++ni) {
      int col = n0 + bn + ni * 16 + fr;
      if (mode1 && col >= 216) continue;
      int rowb = m0 + am + mi * 16 + ro;
      float bv = mode1 ? bcat[col] : b_v[col] * 3.f;
#pragma unroll
      for (int r = 0; r < 4; ++r) {
        int grow = rowb + r;
        float v = acc[mi][ni][r] + bv;
        if (mode1) {
          proj[(size_t)grow * 216 + col] = v;
        } else {
          int b = grow >> 12, nn2 = grow & 4095;
          int h = col >> 5, d = col & 31;
          valsum[(((size_t)(b * NH_ + h) << 12) + nn2) * DH_ + d] = (_Float16)v;
        }
      }
    }
#undef LOADT01
#undef WRITET
#undef COMPUTET
}

// ---------------- O-GEMM: out = inter(fp16 hi/lo) @ W_o + b_o (2-pass) -----
// Grid: 1024 1-D, XCD-swizzled; flat = m*4 + n.
__global__ __launch_bounds__(256, 4) void mgemm2(
    const _Float16* __restrict__ Ahi, const _Float16* __restrict__ Alo,
    const _Float16* __restrict__ Bhs,
    const float* __restrict__ bias, float* __restrict__ Cout) {
  __shared__ _Float16 Ah[64][64], Al[64][64], Bh[64][64];
  const int bid = blockIdx.x;
  const int flat = (bid & 7) * 128 + (bid >> 3);   // XCD-chunked (1024 % 8 == 0)
  const int m0 = (flat >> 2) * 64;
  const int n0 = (flat & 3) * 64;
  const int tid = threadIdx.x, wid = tid >> 6, lane = tid & 63;
  const int am = (wid >> 1) * 32, bn = (wid & 1) * 32;
  const int fr = lane & 15, kg = lane >> 4;

  const int r0s = tid >> 3, c0s = tid & 7;
  const int r1s = r0s + 32;
  const int d0s = r0s * 64 + ((c0s ^ (r0s & 7)) * 8);
  const int d1s = r1s * 64 + ((c0s ^ (r1s & 7)) * 8);

  f32x4 acc[2][2];
#pragma unroll
  for (int i = 0; i < 2; ++i)
#pragma unroll
    for (int j = 0; j < 2; ++j) acc[i][j] = (f32x4)(0.f);

  f16x8 pah[2], pal[2], pbh[2];

#define LOADT2(k0)                                                           \
  {                                                                          \
    size_t a0 = (size_t)(m0 + r0s) * 256 + (k0) + c0s * 8;                   \
    size_t a1 = (size_t)(m0 + r1s) * 256 + (k0) + c0s * 8;                   \
    pah[0] = *(const f16x8*)(Ahi + a0); pal[0] = *(const f16x8*)(Alo + a0);  \
    pah[1] = *(const f16x8*)(Ahi + a1); pal[1] = *(const f16x8*)(Alo + a1);  \
    size_t b0 = (size_t)(n0 + r0s) * 256 + (k0) + c0s * 8;                   \
    size_t b1 = (size_t)(n0 + r1s) * 256 + (k0) + c0s * 8;                   \
    pbh[0] = *(const f16x8*)(Bhs + b0); pbh[1] = *(const f16x8*)(Bhs + b1);  \
  }

#define WRITET2()                                                            \
  {                                                                          \
    *(f16x8*)(&Ah[0][0] + d0s) = pah[0]; *(f16x8*)(&Al[0][0] + d0s) = pal[0];\
    *(f16x8*)(&Ah[0][0] + d1s) = pah[1]; *(f16x8*)(&Al[0][0] + d1s) = pal[1];\
    *(f16x8*)(&Bh[0][0] + d0s) = pbh[0]; *(f16x8*)(&Bh[0][0] + d1s) = pbh[1];\
  }

#define COMPUTET2()                                                          \
  _Pragma("unroll")                                                          \
  for (int ks = 0; ks < 2; ++ks) {                                           \
    const int kc = ks * 4 + kg;                                              \
    f16x8 ah[2], al[2], bh[2];                                               \
    _Pragma("unroll")                                                        \
    for (int mi = 0; mi < 2; ++mi) {                                         \
      int m = am + mi * 16 + fr;                                             \
      int o = m * 64 + ((kc ^ (m & 7)) * 8);                                 \
      ah[mi] = *(const f16x8*)(&Ah[0][0] + o);                               \
      al[mi] = *(const f16x8*)(&Al[0][0] + o);                               \
    }                                                                        \
    _Pragma("unroll")                                                        \
    for (int ni = 0; ni < 2; ++ni) {                                         \
      int nn = bn + ni * 16 + fr;                                            \
      int o = nn * 64 + ((kc ^ (nn & 7)) * 8);                               \
      bh[ni] = *(const f16x8*)(&Bh[0][0] + o);                               \
    }                                                                        \
    _Pragma("unroll")                                                        \
    for (int mi = 0; mi < 2; ++mi)                                           \
      _Pragma("unroll")                                                      \
      for (int ni = 0; ni < 2; ++ni) {                                       \
        acc[mi][ni] = __builtin_amdgcn_mfma_f32_16x16x32_f16(ah[mi], bh[ni], acc[mi][ni], 0, 0, 0);\
        acc[mi][ni] = __builtin_amdgcn_mfma_f32_16x16x32_f16(al[mi], bh[ni], acc[mi][ni], 0, 0, 0);\
      }                                                                      \
  }

  LOADT2(0);
  WRITET2();
  __syncthreads();
#pragma unroll
  for (int t = 0; t < 4; ++t) {
    if (t < 3) LOADT2((t + 1) * 64);
    COMPUTET2();
    __syncthreads();
    if (t < 3) { WRITET2(); __syncthreads(); }
  }

  const int ro = kg * 4;
#pragma unroll
  for (int mi = 0; mi < 2; ++mi)
#pragma unroll
    for (int ni = 0; ni < 2; ++ni) {
      int col = n0 + bn + ni * 16 + fr;
      int rowb = m0 + am + mi * 16 + ro;
      float bv = bias[col];
#pragma unroll
      for (int r = 0; r < 4; ++r)
        Cout[(size_t)(rowb + r) * 256 + col] = acc[mi][ni][r] + bv;
    }
#undef LOADT2
#undef WRITET2
#undef COMPUTET2
}

// ---------------- sampler: 4 px / block, fp16 gathers, fp16 hi/lo out ------
struct IW { int idx; float w; };

__global__ __launch_bounds__(256) void sample4(const _Float16* __restrict__ valsum,
                                               const float* __restrict__ proj,
                                               _Float16* __restrict__ ihi,
                                               _Float16* __restrict__ ilo) {
  const int bid = blockIdx.x;                 // 4096 blocks
  const int wv = threadIdx.x >> 6;
  const int lane = threadIdx.x & 63;
  const int row = ((bid & 7) << 11) + ((bid >> 3) << 2) + wv;  // XCD-chunked
  const int b = row >> 12, n = row & 4095;

  __shared__ IW cwi[4][72][4];
  __shared__ float sap[4][76];

  const float* pr = proj + (size_t)row * 216;
  if (lane < 8) {
    const float* pa = pr + 144 + lane * 9;
    float lg[9], mx = -1e30f;
#pragma unroll
    for (int p = 0; p < 9; ++p) { lg[p] = pa[p]; mx = fmaxf(mx, lg[p]); }
    float s = 0.f;
#pragma unroll
    for (int p = 0; p < 9; ++p) { lg[p] = __expf(lg[p] - mx); s += lg[p]; }
    float inv = 1.f / s;
#pragma unroll
    for (int p = 0; p < 9; ++p) sap[wv][lane * 9 + p] = lg[p] * inv;
  }
  __syncthreads();
  for (int e = lane; e < 72; e += 64) {
    float ox = pr[e * 2], oy = pr[e * 2 + 1];
    float gx = (float)(n & 63) + ox * 31.5f;
    float gy = (float)(n >> 6) + oy * 31.5f;
    float fx0 = floorf(gx), fy0 = floorf(gy);
    float wx1 = gx - fx0, wy1 = gy - fy0;
    float wx0 = 1.f - wx1, wy0 = 1.f - wy1;
    int x0 = (int)fx0, y0 = (int)fy0, x1 = x0 + 1, y1 = y0 + 1;
    bool vx0 = (x0 >= 0) & (x0 < 64), vx1 = (x1 >= 0) & (x1 < 64);
    bool vy0 = (y0 >= 0) & (y0 < 64), vy1 = (y1 >= 0) & (y1 < 64);
    int x0c = min(max(x0, 0), 63), x1c = min(max(x1, 0), 63);
    int y0c = min(max(y0, 0), 63), y1c = min(max(y1, 0), 63);
    const float a = sap[wv][e];
    cwi[wv][e][0] = IW{(y0c * 64 + x0c) * DH_, (vx0 & vy0) ? wx0 * wy0 * a : 0.f};
    cwi[wv][e][1] = IW{(y0c * 64 + x1c) * DH_, (vx1 & vy0) ? wx1 * wy0 * a : 0.f};
    cwi[wv][e][2] = IW{(y1c * 64 + x0c) * DH_, (vx0 & vy1) ? wx0 * wy1 * a : 0.f};
    cwi[wv][e][3] = IW{(y1c * 64 + x1c) * DH_, (vx1 & vy1) ? wx1 * wy1 * a : 0.f};
  }
  __syncthreads();

  const int h = lane >> 3, d4 = (lane & 7) * 4;
  const _Float16* vb = valsum + (((size_t)(b * NH_ + h)) << 12) * DH_ + d4;
  float ax = 0.f, ay = 0.f, az = 0.f, aw = 0.f;
#pragma unroll
  for (int pb = 0; pb < 9; pb += 3) {
    f16x4 v[12]; float w[12];
#pragma unroll
    for (int q = 0; q < 3; ++q) {
      const int hp = h * 9 + pb + q;
#pragma unroll
      for (int c = 0; c < 4; ++c) {
        IW e = cwi[wv][hp][c];
        v[q * 4 + c] = *(const f16x4*)(vb + e.idx);
        w[q * 4 + c] = e.w;
      }
    }
#pragma unroll
    for (int j = 0; j < 12; ++j) {
      ax += w[j] * (float)v[j][0]; ay += w[j] * (float)v[j][1];
      az += w[j] * (float)v[j][2]; aw += w[j] * (float)v[j][3];
    }
  }
  float av[4] = {ax, ay, az, aw};
  f16x4 hv, lv;
#pragma unroll
  for (int j = 0; j < 4; ++j) {
    HL r = fsplit(av[j]);
    hv[j] = r.h; lv[j] = r.l;
  }
  const size_t o = (size_t)row * 256 + lane * 4;   // == row*256 + h*32 + d4
  *(f16x4*)(ihi + o) = hv;
  *(f16x4*)(ilo + o) = lv;
}

extern "C" void kernel_launch(void* const* d_in, const int* in_sizes, int n_in,
                              void* d_out, int out_size, void* d_ws, size_t ws_size,
                              hipStream_t stream) {
  const float* x      = (const float*)d_in[0];
  const float* W_off  = (const float*)d_in[1];
  const float* b_off  = (const float*)d_in[2];
  const float* W_attn = (const float*)d_in[3];
  const float* b_attn = (const float*)d_in[4];
  const float* W_v    = (const float*)d_in[5];
  const float* b_v    = (const float*)d_in[6];
  const float* W_o    = (const float*)d_in[7];
  const float* b_o    = (const float*)d_in[8];
  float* out = (float*)d_out;

  // ---- workspace layout
  _Float16* valsum = (_Float16*)d_ws;                   // 16384*256 fp16 (8 MB)
  float* proj    = (float*)(valsum + (size_t)MM_ * 256);// 16384*216 f32
  float* bcat    = proj + (size_t)MM_ * 216;            // 256 f32
  _Float16* ash = (_Float16*)(bcat + 256);              // 16384*256 fp16
  _Float16* asl = ash + (size_t)MM_ * 256;
  _Float16* xmh = asl + (size_t)MM_ * 256;              // 16384*256 fp16
  _Float16* xml = xmh + (size_t)MM_ * 256;
  _Float16* wv  = xml + (size_t)MM_ * 256;              // 256*256
  _Float16* wch = wv + 65536;                           // 216*256 hi
  _Float16* wcl = wch + 55296;                          // 216*256 lo
  _Float16* wo  = wcl + 55296;                          // 256*256
  // inter hi/lo alias ash/asl (dead after mgemm01)
  _Float16* ihi = ash;
  _Float16* ilo = asl;

  prep<<<dim3(4352), dim3(256), 0, stream>>>(x, W_off, W_attn, W_v, W_o, b_off, b_attn,
                                             ash, asl, xmh, xml,
                                             wv, wch, wcl, wo, bcat);
  mgemm01<<<dim3(2048), dim3(256), 0, stream>>>(ash, asl, xmh, xml, wv, wch, wcl,
                                                b_v, bcat, valsum, proj);
  sample4<<<dim3(4096), dim3(256), 0, stream>>>(valsum, proj, ihi, ilo);
  mgemm2<<<dim3(1024), dim3(256), 0, stream>>>(ihi, ilo, wo, b_o, out);
}